// Round 14
// baseline (64.233 us; speedup 1.0000x reference)
//
#include <hip/hip_runtime.h>
#include <hip/hip_bf16.h>

// QueryGrouper: ball_query (first-K-in-index-order within radius) + grouping.
// B=4, N=8192, M=2048, C=128, K=32, radius=0.1, use_xyz from out_size.
//
// R14: ball with Q=4 queries/wave. R13's ball was LDS-issue-bound (~29us on
// the per-CU LDS pipe: each wave re-read every point for its single query).
// Now each point read serves 4 queries (coords/cnt/ff wave-uniform -> SGPR),
// xyz packed float4 in LDS (1 ds_read_b128 vs 3 ds_read_b32), wave-uniform
// early-out when all 4 queries have K hits. Gather: R12-validated one-pass
// (at write roofline: FETCH 9.3MB, 6.26 TB/s).

#define K_NEIGH 32
// f32(0.010000000000000002) — matches JAX weak-typed radius*radius bit-exactly.
#define R2_F32 0.009999999776482582f
#define CCH 128
#define NPTS 8192
#define MQ 2048

// ---- fast-path ball: 512 thr = 8 waves x 4 queries = 32 queries/block ----
__global__ __launch_bounds__(512, 8) void ball_q4_kernel(
    const float* __restrict__ xyz,      // (B,3,N)
    const float* __restrict__ new_xyz,  // (B,3,M)
    int* __restrict__ idxb,             // (B*M, K)
    float* __restrict__ out0,           // (B, CO, M, K)
    float* __restrict__ out1,           // (B, 3, M, K)
    int use_xyz)
{
    constexpr int CH = 2048;
    __shared__ float4 pts[CH];              // 32 KB, {x,y,z,0} per point
    __shared__ int lidx[8][4][K_NEIGH];     // 4 KB

    const int tid  = threadIdx.x;
    const int wave = tid >> 6;
    const int lane = tid & 63;
    const int q0 = blockIdx.x * 32 + wave * 4;   // 4 queries of this wave
    const int b  = q0 / MQ;                      // 32 | 2048 -> same b per block
    const int m0 = q0 - b * MQ;

    const float* x0 = xyz + (size_t)b * 3 * NPTS;
    const float* x1 = x0 + NPTS;
    const float* x2 = x1 + NPTS;
    const float* nb = new_xyz + (size_t)b * 3 * MQ;

    float qx[4], qy[4], qz[4];
    int   cnt[4] = {0, 0, 0, 0};
    int   ff [4] = {0, 0, 0, 0};
    #pragma unroll
    for (int j = 0; j < 4; ++j) {
        qx[j] = nb[m0 + j];
        qy[j] = nb[MQ + m0 + j];
        qz[j] = nb[2 * MQ + m0 + j];
    }
    const unsigned long long below = (1ull << lane) - 1ull;

    for (int c0 = 0; c0 < NPTS; c0 += CH) {
        // stage chunk: thread t packs points 4t..4t+3 (all reads coalesced)
        {
            const int p0 = tid * 4;
            const float4 vx = *(const float4*)&x0[c0 + p0];
            const float4 vy = *(const float4*)&x1[c0 + p0];
            const float4 vz = *(const float4*)&x2[c0 + p0];
            pts[p0 + 0] = make_float4(vx.x, vy.x, vz.x, 0.f);
            pts[p0 + 1] = make_float4(vx.y, vy.y, vz.y, 0.f);
            pts[p0 + 2] = make_float4(vx.z, vy.z, vz.z, 0.f);
            pts[p0 + 3] = make_float4(vx.w, vy.w, vz.w, 0.f);
        }
        __syncthreads();

        const bool alldone = (cnt[0] >= K_NEIGH) && (cnt[1] >= K_NEIGH) &&
                             (cnt[2] >= K_NEIGH) && (cnt[3] >= K_NEIGH);
        if (!alldone) {                      // wave-uniform guard
            for (int g = 0; g < CH; g += 128) {
                const float4 pa = pts[g + lane];
                const float4 pb = pts[g + 64 + lane];
                const int gia = c0 + g + lane;

                #pragma unroll
                for (int j = 0; j < 4; ++j) {
                    // match JAX: sub, square (no FMA), left-to-right sum, f32 RN
                    #define D2(P) \
                        __fadd_rn(__fadd_rn(__fmul_rn((P).x - qx[j], (P).x - qx[j]), \
                                            __fmul_rn((P).y - qy[j], (P).y - qy[j])), \
                                  __fmul_rn((P).z - qz[j], (P).z - qz[j]))
                    const bool ina = D2(pa) < R2_F32;
                    const bool inb = D2(pb) < R2_F32;
                    #undef D2
                    const unsigned long long ma = __ballot(ina);
                    const unsigned long long mb = __ballot(inb);
                    if (ma) {
                        if (cnt[j] == 0) ff[j] = gia - lane + (__ffsll(ma) - 1);
                        if (ina) {
                            const int pos = cnt[j] + __popcll(ma & below);
                            if (pos < K_NEIGH) lidx[wave][j][pos] = gia;
                        }
                        cnt[j] += __popcll(ma);
                    }
                    if (mb) {
                        if (cnt[j] == 0) ff[j] = gia - lane + 64 + (__ffsll(mb) - 1);
                        if (inb) {
                            const int pos = cnt[j] + __popcll(mb & below);
                            if (pos < K_NEIGH) lidx[wave][j][pos] = gia + 64;
                        }
                        cnt[j] += __popcll(mb);
                    }
                }
            }
        }
        __syncthreads();
    }

    asm volatile("s_waitcnt lgkmcnt(0)" ::: "memory");

    // epilogue: 4 queries, lanes 0-31 write each (index order preserved)
    const size_t MK = (size_t)MQ * K_NEIGH;
    #pragma unroll
    for (int j = 0; j < 4; ++j) {
        if (lane < K_NEIGH) {
            const int m = m0 + j;
            const int jdx = (lane < cnt[j]) ? lidx[wave][j][lane] : ff[j];
            idxb[((size_t)b * MQ + m) * K_NEIGH + lane] = jdx;
            const float gx = x0[jdx] - qx[j];
            const float gy = x1[jdx] - qy[j];
            const float gz = x2[jdx] - qz[j];
            const size_t o1 = (size_t)b * 3 * MK + (size_t)m * K_NEIGH + lane;
            out1[o1]          = gx;
            out1[o1 + MK]     = gy;
            out1[o1 + 2 * MK] = gz;
            if (use_xyz) {
                const size_t o0 = (size_t)b * (CCH + 3) * MK + (size_t)m * K_NEIGH + lane;
                out0[o0]          = gx;
                out0[o0 + MK]     = gy;
                out0[o0 + 2 * MK] = gz;
            }
        }
    }
}

// ---- fallback ball (any shape): global loads, 1 query/wave ----
__global__ __launch_bounds__(256) void ball_query_xyz_kernel(
    const float* __restrict__ xyz, const float* __restrict__ new_xyz,
    int* __restrict__ idxb, float* __restrict__ out0, float* __restrict__ out1,
    int N, int M, int C, int use_xyz)
{
    __shared__ int lidx[4][K_NEIGH];
    const int wave = threadIdx.x >> 6;
    const int lane = threadIdx.x & 63;
    const int q = blockIdx.x * 4 + wave;
    const int b = q / M;
    const int m = q - b * M;

    const float* xb = xyz + (size_t)b * 3 * N;
    const float* x0 = xb;
    const float* x1 = xb + N;
    const float* x2 = xb + 2 * N;
    const float* nb = new_xyz + (size_t)b * 3 * M;
    const float qx = nb[m];
    const float qy = nb[M + m];
    const float qz = nb[2 * M + m];

    int cnt = 0;
    int ff  = 0;
    const unsigned long long below = (1ull << lane) - 1ull;

    for (int t0 = 0; t0 < N; t0 += 64) {
        const int i = t0 + lane;
        const float dx = x0[i] - qx;
        const float dy = x1[i] - qy;
        const float dz = x2[i] - qz;
        const float d2 = __fadd_rn(__fadd_rn(__fmul_rn(dx, dx), __fmul_rn(dy, dy)),
                                   __fmul_rn(dz, dz));
        const bool in_ball = d2 < R2_F32;
        const unsigned long long mask = __ballot(in_ball);
        if (mask) {
            if (cnt == 0) ff = t0 + (__ffsll(mask) - 1);
            if (in_ball) {
                const int pos = cnt + __popcll(mask & below);
                if (pos < K_NEIGH) lidx[wave][pos] = i;
            }
            cnt += __popcll(mask);
            if (cnt >= K_NEIGH) break;
        }
    }

    asm volatile("s_waitcnt lgkmcnt(0)" ::: "memory");

    if (lane < K_NEIGH) {
        const int j = (lane < cnt) ? lidx[wave][lane] : ff;
        idxb[(size_t)q * K_NEIGH + lane] = j;
        const float gx = x0[j] - qx;
        const float gy = x1[j] - qy;
        const float gz = x2[j] - qz;
        const size_t MK = (size_t)M * K_NEIGH;
        const size_t o1 = (size_t)b * 3 * MK + (size_t)m * K_NEIGH + lane;
        out1[o1]          = gx;
        out1[o1 + MK]     = gy;
        out1[o1 + 2 * MK] = gz;
        if (use_xyz) {
            const size_t o0 = (size_t)b * (C + 3) * MK + (size_t)m * K_NEIGH + lane;
            out0[o0]          = gx;
            out0[o0 + MK]     = gy;
            out0[o0 + 2 * MK] = gz;
        }
    }
}

// Fixed geometry: B=4, N=8192, M=2048, C=128. Grid = 256 blocks x 1024 thr.
// One pass, plain float4 stores (R12-validated: runs at write roofline).
__global__ __launch_bounds__(1024, 4) void gather_onepass_kernel(
    const float* __restrict__ feat,  // (B,C,N)
    const int* __restrict__ idxb,    // (B*M,K)
    float* __restrict__ out0,        // (B,CO,M,K)
    int use_xyz)
{
    __shared__ float sf[2 * NPTS];   // 64 KB: [0,N) = ch c0, [N,2N) = ch c0+1

    const int t   = threadIdx.x;
    const int bid = blockIdx.x;
    const int b   = (bid & 7) >> 1;                 // 0..3
    const int cg  = ((bid >> 3) << 1) | (bid & 1);  // 0..63
    const int c0  = cg * 2;

    // ---- Phase A: idx prefetch (regs) + feat stage (LDS) ----
    const int4* ip4 = (const int4*)(idxb + (size_t)b * MQ * K_NEIGH);
    int4 jj[16];
    #pragma unroll
    for (int i = 0; i < 16; ++i) jj[i] = ip4[i * 1024 + t];

    const float4* fv = (const float4*)(feat + ((size_t)b * CCH + c0) * NPTS);
    #pragma unroll
    for (int r = 0; r < 4; ++r)
        ((float4*)sf)[t + r * 1024] = fv[t + r * 1024];
    __syncthreads();

    // ---- Phase B: pure LDS-read + plain float4 stores ----
    const size_t MK = (size_t)MQ * K_NEIGH;
    const int CO   = use_xyz ? (CCH + 3) : CCH;
    const int coff = use_xyz ? 3 : 0;
    float* o0 = out0 + ((size_t)b * CO + coff + c0) * MK;
    float* o1 = o0 + MK;

    #pragma unroll
    for (int i = 0; i < 16; ++i) {
        const int p = i * 4096 + 4 * t;      // flat (m,k) base, k-aligned x4
        const int4 j4 = jj[i];
        float4 s0, s1;
        s0.x = sf[j4.x]; s0.y = sf[j4.y]; s0.z = sf[j4.z]; s0.w = sf[j4.w];
        s1.x = sf[NPTS + j4.x]; s1.y = sf[NPTS + j4.y];
        s1.z = sf[NPTS + j4.z]; s1.w = sf[NPTS + j4.w];
        *(float4*)(o0 + p) = s0;
        *(float4*)(o1 + p) = s1;
    }
}

// Fallback gather (any shape): R1 structure.
__global__ __launch_bounds__(256) void gather_kernel(
    const float* __restrict__ xyz, const float* __restrict__ new_xyz,
    const float* __restrict__ feat, const int* __restrict__ idxb,
    float* __restrict__ out0, float* __restrict__ out1,
    int N, int M, int C, int use_xyz)
{
    const int tid = threadIdx.x;
    const int k = tid & 31;
    const int mloc = tid >> 5;
    const int mchunks = M >> 3;
    const int b = blockIdx.x / mchunks;
    const int m = (blockIdx.x - b * mchunks) * 8 + mloc;
    const int q = b * M + m;
    const int j = idxb[(size_t)q * K_NEIGH + k];
    const size_t xb = (size_t)b * 3 * N;
    const size_t nb = (size_t)b * 3 * M;
    const float gx = xyz[xb + j]         - new_xyz[nb + m];
    const float gy = xyz[xb + N + j]     - new_xyz[nb + M + m];
    const float gz = xyz[xb + 2 * N + j] - new_xyz[nb + 2 * M + m];
    const size_t MK = (size_t)M * K_NEIGH;
    const size_t o1 = (size_t)b * 3 * MK + (size_t)m * K_NEIGH + k;
    out1[o1] = gx; out1[o1 + MK] = gy; out1[o1 + 2 * MK] = gz;
    const int CO = use_xyz ? (C + 3) : C;
    size_t o0 = (size_t)b * CO * MK + (size_t)m * K_NEIGH + k;
    if (use_xyz) {
        out0[o0] = gx; out0[o0 + MK] = gy; out0[o0 + 2 * MK] = gz;
        o0 += 3 * MK;
    }
    const float* fb = feat + (size_t)b * C * N;
    #pragma unroll 4
    for (int c = 0; c < C; c += 4) {
        const float v0 = fb[(size_t)c * N + j];
        const float v1 = fb[(size_t)(c + 1) * N + j];
        const float v2 = fb[(size_t)(c + 2) * N + j];
        const float v3 = fb[(size_t)(c + 3) * N + j];
        out0[o0 + (size_t)c * MK]       = v0;
        out0[o0 + (size_t)(c + 1) * MK] = v1;
        out0[o0 + (size_t)(c + 2) * MK] = v2;
        out0[o0 + (size_t)(c + 3) * MK] = v3;
    }
}

extern "C" void kernel_launch(void* const* d_in, const int* in_sizes, int n_in,
                              void* d_out, int out_size, void* d_ws, size_t ws_size,
                              hipStream_t stream) {
    const float* new_xyz = (const float*)d_in[0];   // (B,3,M)
    const float* xyz     = (const float*)d_in[1];   // (B,3,N)
    const float* feat    = (const float*)d_in[2];   // (B,C,N)

    const int B = 4;                       // fixed by harness setup
    const int M = in_sizes[0] / (3 * B);   // 2048
    const int N = in_sizes[1] / (3 * B);   // 8192
    const int C = in_sizes[2] / (B * N);   // 128

    const long long sz_with = (long long)B * (C + 6) * M * K_NEIGH;
    const int use_xyz = (out_size == sz_with) ? 1 : 0;

    float* out0 = (float*)d_out;
    float* out1 = out0 + (size_t)B * (use_xyz ? (C + 3) : C) * M * K_NEIGH;

    int* idxb = (int*)d_ws;  // B*M*K ints = 1 MB
    const size_t idx_bytes = (size_t)B * M * K_NEIGH * sizeof(int);

    const bool fast = (B == 4) && (N == NPTS) && (M == MQ) && (C == CCH)
                      && (ws_size >= idx_bytes);

    if (fast) {
        ball_q4_kernel<<<(B * MQ) / 32, 512, 0, stream>>>(
            xyz, new_xyz, idxb, out0, out1, use_xyz);
        gather_onepass_kernel<<<256, 1024, 0, stream>>>(feat, idxb, out0, use_xyz);
    } else {
        ball_query_xyz_kernel<<<(B * M) / 4, 256, 0, stream>>>(
            xyz, new_xyz, idxb, out0, out1, N, M, C, use_xyz);
        gather_kernel<<<B * (M / 8), 256, 0, stream>>>(xyz, new_xyz, feat, idxb,
                                                       out0, out1, N, M, C, use_xyz);
    }
}

// Round 15
// 57.179 us; speedup vs baseline: 1.1234x; 1.1234x over previous
//
#include <hip/hip_runtime.h>
#include <hip/hip_bf16.h>

// QueryGrouper: ball_query (first-K-in-index-order within radius) + grouping.
// B=4, N=8192, M=2048, C=128, K=32, radius=0.1, use_xyz from out_size.
//
// R15: ball with Q=2 queries/wave (R14's Q=4 halved occupancy to 8 waves/CU
// and went latency-bound; R13's Q=1 was LDS-issue-bound at 32 waves/CU).
// Q=2 -> 4096 waves = 16/CU (4/SIMD): LDS reads ~10us overlapping ~8us VALU
// floor. float4-packed pts (1 ds_read_b128 per 64 pts per wave). Gather:
// R12-validated one-pass at the write roofline (FETCH 9.3MB, 6.26 TB/s).

#define K_NEIGH 32
// f32(0.010000000000000002) — matches JAX weak-typed radius*radius bit-exactly.
#define R2_F32 0.009999999776482582f
#define CCH 128
#define NPTS 8192
#define MQ 2048

// ---- fast-path ball: 512 thr = 8 waves x 2 queries = 16 queries/block ----
__global__ __launch_bounds__(512, 4) void ball_q2_kernel(
    const float* __restrict__ xyz,      // (B,3,N)
    const float* __restrict__ new_xyz,  // (B,3,M)
    int* __restrict__ idxb,             // (B*M, K)
    float* __restrict__ out0,           // (B, CO, M, K)
    float* __restrict__ out1,           // (B, 3, M, K)
    int use_xyz)
{
    constexpr int CH = 2048;
    __shared__ float4 pts[CH];              // 32 KB, {x,y,z,0} per point
    __shared__ int lidx[8][2][K_NEIGH];     // 2 KB

    const int tid  = threadIdx.x;
    const int wave = tid >> 6;
    const int lane = tid & 63;
    const int q0 = blockIdx.x * 16 + wave * 2;   // 2 queries of this wave
    const int b  = q0 / MQ;                      // 16 | 2048 -> same b per block
    const int m0 = q0 - b * MQ;

    const float* x0 = xyz + (size_t)b * 3 * NPTS;
    const float* x1 = x0 + NPTS;
    const float* x2 = x1 + NPTS;
    const float* nb = new_xyz + (size_t)b * 3 * MQ;

    float qx[2], qy[2], qz[2];
    int   cnt[2] = {0, 0};
    int   ff [2] = {0, 0};
    #pragma unroll
    for (int j = 0; j < 2; ++j) {
        qx[j] = nb[m0 + j];
        qy[j] = nb[MQ + m0 + j];
        qz[j] = nb[2 * MQ + m0 + j];
    }
    const unsigned long long below = (1ull << lane) - 1ull;

    for (int c0 = 0; c0 < NPTS; c0 += CH) {
        // stage chunk: thread t packs points 4t..4t+3 (all reads coalesced)
        {
            const int p0 = tid * 4;
            const float4 vx = *(const float4*)&x0[c0 + p0];
            const float4 vy = *(const float4*)&x1[c0 + p0];
            const float4 vz = *(const float4*)&x2[c0 + p0];
            pts[p0 + 0] = make_float4(vx.x, vy.x, vz.x, 0.f);
            pts[p0 + 1] = make_float4(vx.y, vy.y, vz.y, 0.f);
            pts[p0 + 2] = make_float4(vx.z, vy.z, vz.z, 0.f);
            pts[p0 + 3] = make_float4(vx.w, vy.w, vz.w, 0.f);
        }
        __syncthreads();

        const bool alldone = (cnt[0] >= K_NEIGH) && (cnt[1] >= K_NEIGH);
        if (!alldone) {                      // wave-uniform guard
            for (int g = 0; g < CH; g += 128) {
                const float4 pa = pts[g + lane];
                const float4 pb = pts[g + 64 + lane];
                const int gia = c0 + g + lane;

                #pragma unroll
                for (int j = 0; j < 2; ++j) {
                    // match JAX: sub, square (no FMA), left-to-right sum, f32 RN
                    #define D2(P) \
                        __fadd_rn(__fadd_rn(__fmul_rn((P).x - qx[j], (P).x - qx[j]), \
                                            __fmul_rn((P).y - qy[j], (P).y - qy[j])), \
                                  __fmul_rn((P).z - qz[j], (P).z - qz[j]))
                    const bool ina = D2(pa) < R2_F32;
                    const bool inb = D2(pb) < R2_F32;
                    #undef D2
                    const unsigned long long ma = __ballot(ina);
                    const unsigned long long mb = __ballot(inb);
                    if (ma) {
                        if (cnt[j] == 0) ff[j] = gia - lane + (__ffsll(ma) - 1);
                        if (ina) {
                            const int pos = cnt[j] + __popcll(ma & below);
                            if (pos < K_NEIGH) lidx[wave][j][pos] = gia;
                        }
                        cnt[j] += __popcll(ma);
                    }
                    if (mb) {
                        if (cnt[j] == 0) ff[j] = gia - lane + 64 + (__ffsll(mb) - 1);
                        if (inb) {
                            const int pos = cnt[j] + __popcll(mb & below);
                            if (pos < K_NEIGH) lidx[wave][j][pos] = gia + 64;
                        }
                        cnt[j] += __popcll(mb);
                    }
                }
            }
        }
        __syncthreads();
    }

    asm volatile("s_waitcnt lgkmcnt(0)" ::: "memory");

    // epilogue: 2 queries, lanes 0-31 write each (index order preserved)
    const size_t MK = (size_t)MQ * K_NEIGH;
    #pragma unroll
    for (int j = 0; j < 2; ++j) {
        if (lane < K_NEIGH) {
            const int m = m0 + j;
            const int jdx = (lane < cnt[j]) ? lidx[wave][j][lane] : ff[j];
            idxb[((size_t)b * MQ + m) * K_NEIGH + lane] = jdx;
            const float gx = x0[jdx] - qx[j];
            const float gy = x1[jdx] - qy[j];
            const float gz = x2[jdx] - qz[j];
            const size_t o1 = (size_t)b * 3 * MK + (size_t)m * K_NEIGH + lane;
            out1[o1]          = gx;
            out1[o1 + MK]     = gy;
            out1[o1 + 2 * MK] = gz;
            if (use_xyz) {
                const size_t o0 = (size_t)b * (CCH + 3) * MK + (size_t)m * K_NEIGH + lane;
                out0[o0]          = gx;
                out0[o0 + MK]     = gy;
                out0[o0 + 2 * MK] = gz;
            }
        }
    }
}

// ---- fallback ball (any shape): global loads, 1 query/wave ----
__global__ __launch_bounds__(256) void ball_query_xyz_kernel(
    const float* __restrict__ xyz, const float* __restrict__ new_xyz,
    int* __restrict__ idxb, float* __restrict__ out0, float* __restrict__ out1,
    int N, int M, int C, int use_xyz)
{
    __shared__ int lidx[4][K_NEIGH];
    const int wave = threadIdx.x >> 6;
    const int lane = threadIdx.x & 63;
    const int q = blockIdx.x * 4 + wave;
    const int b = q / M;
    const int m = q - b * M;

    const float* xb = xyz + (size_t)b * 3 * N;
    const float* x0 = xb;
    const float* x1 = xb + N;
    const float* x2 = xb + 2 * N;
    const float* nb = new_xyz + (size_t)b * 3 * M;
    const float qx = nb[m];
    const float qy = nb[M + m];
    const float qz = nb[2 * M + m];

    int cnt = 0;
    int ff  = 0;
    const unsigned long long below = (1ull << lane) - 1ull;

    for (int t0 = 0; t0 < N; t0 += 64) {
        const int i = t0 + lane;
        const float dx = x0[i] - qx;
        const float dy = x1[i] - qy;
        const float dz = x2[i] - qz;
        const float d2 = __fadd_rn(__fadd_rn(__fmul_rn(dx, dx), __fmul_rn(dy, dy)),
                                   __fmul_rn(dz, dz));
        const bool in_ball = d2 < R2_F32;
        const unsigned long long mask = __ballot(in_ball);
        if (mask) {
            if (cnt == 0) ff = t0 + (__ffsll(mask) - 1);
            if (in_ball) {
                const int pos = cnt + __popcll(mask & below);
                if (pos < K_NEIGH) lidx[wave][pos] = i;
            }
            cnt += __popcll(mask);
            if (cnt >= K_NEIGH) break;
        }
    }

    asm volatile("s_waitcnt lgkmcnt(0)" ::: "memory");

    if (lane < K_NEIGH) {
        const int j = (lane < cnt) ? lidx[wave][lane] : ff;
        idxb[(size_t)q * K_NEIGH + lane] = j;
        const float gx = x0[j] - qx;
        const float gy = x1[j] - qy;
        const float gz = x2[j] - qz;
        const size_t MK = (size_t)M * K_NEIGH;
        const size_t o1 = (size_t)b * 3 * MK + (size_t)m * K_NEIGH + lane;
        out1[o1]          = gx;
        out1[o1 + MK]     = gy;
        out1[o1 + 2 * MK] = gz;
        if (use_xyz) {
            const size_t o0 = (size_t)b * (C + 3) * MK + (size_t)m * K_NEIGH + lane;
            out0[o0]          = gx;
            out0[o0 + MK]     = gy;
            out0[o0 + 2 * MK] = gz;
        }
    }
}

// Fixed geometry: B=4, N=8192, M=2048, C=128. Grid = 256 blocks x 1024 thr.
// One pass, plain float4 stores (R12-validated: runs at write roofline).
__global__ __launch_bounds__(1024, 4) void gather_onepass_kernel(
    const float* __restrict__ feat,  // (B,C,N)
    const int* __restrict__ idxb,    // (B*M,K)
    float* __restrict__ out0,        // (B,CO,M,K)
    int use_xyz)
{
    __shared__ float sf[2 * NPTS];   // 64 KB: [0,N) = ch c0, [N,2N) = ch c0+1

    const int t   = threadIdx.x;
    const int bid = blockIdx.x;
    const int b   = (bid & 7) >> 1;                 // 0..3
    const int cg  = ((bid >> 3) << 1) | (bid & 1);  // 0..63
    const int c0  = cg * 2;

    // ---- Phase A: idx prefetch (regs) + feat stage (LDS) ----
    const int4* ip4 = (const int4*)(idxb + (size_t)b * MQ * K_NEIGH);
    int4 jj[16];
    #pragma unroll
    for (int i = 0; i < 16; ++i) jj[i] = ip4[i * 1024 + t];

    const float4* fv = (const float4*)(feat + ((size_t)b * CCH + c0) * NPTS);
    #pragma unroll
    for (int r = 0; r < 4; ++r)
        ((float4*)sf)[t + r * 1024] = fv[t + r * 1024];
    __syncthreads();

    // ---- Phase B: pure LDS-read + plain float4 stores ----
    const size_t MK = (size_t)MQ * K_NEIGH;
    const int CO   = use_xyz ? (CCH + 3) : CCH;
    const int coff = use_xyz ? 3 : 0;
    float* o0 = out0 + ((size_t)b * CO + coff + c0) * MK;
    float* o1 = o0 + MK;

    #pragma unroll
    for (int i = 0; i < 16; ++i) {
        const int p = i * 4096 + 4 * t;      // flat (m,k) base, k-aligned x4
        const int4 j4 = jj[i];
        float4 s0, s1;
        s0.x = sf[j4.x]; s0.y = sf[j4.y]; s0.z = sf[j4.z]; s0.w = sf[j4.w];
        s1.x = sf[NPTS + j4.x]; s1.y = sf[NPTS + j4.y];
        s1.z = sf[NPTS + j4.z]; s1.w = sf[NPTS + j4.w];
        *(float4*)(o0 + p) = s0;
        *(float4*)(o1 + p) = s1;
    }
}

// Fallback gather (any shape): R1 structure.
__global__ __launch_bounds__(256) void gather_kernel(
    const float* __restrict__ xyz, const float* __restrict__ new_xyz,
    const float* __restrict__ feat, const int* __restrict__ idxb,
    float* __restrict__ out0, float* __restrict__ out1,
    int N, int M, int C, int use_xyz)
{
    const int tid = threadIdx.x;
    const int k = tid & 31;
    const int mloc = tid >> 5;
    const int mchunks = M >> 3;
    const int b = blockIdx.x / mchunks;
    const int m = (blockIdx.x - b * mchunks) * 8 + mloc;
    const int q = b * M + m;
    const int j = idxb[(size_t)q * K_NEIGH + k];
    const size_t xb = (size_t)b * 3 * N;
    const size_t nb = (size_t)b * 3 * M;
    const float gx = xyz[xb + j]         - new_xyz[nb + m];
    const float gy = xyz[xb + N + j]     - new_xyz[nb + M + m];
    const float gz = xyz[xb + 2 * N + j] - new_xyz[nb + 2 * M + m];
    const size_t MK = (size_t)M * K_NEIGH;
    const size_t o1 = (size_t)b * 3 * MK + (size_t)m * K_NEIGH + k;
    out1[o1] = gx; out1[o1 + MK] = gy; out1[o1 + 2 * MK] = gz;
    const int CO = use_xyz ? (C + 3) : C;
    size_t o0 = (size_t)b * CO * MK + (size_t)m * K_NEIGH + k;
    if (use_xyz) {
        out0[o0] = gx; out0[o0 + MK] = gy; out0[o0 + 2 * MK] = gz;
        o0 += 3 * MK;
    }
    const float* fb = feat + (size_t)b * C * N;
    #pragma unroll 4
    for (int c = 0; c < C; c += 4) {
        const float v0 = fb[(size_t)c * N + j];
        const float v1 = fb[(size_t)(c + 1) * N + j];
        const float v2 = fb[(size_t)(c + 2) * N + j];
        const float v3 = fb[(size_t)(c + 3) * N + j];
        out0[o0 + (size_t)c * MK]       = v0;
        out0[o0 + (size_t)(c + 1) * MK] = v1;
        out0[o0 + (size_t)(c + 2) * MK] = v2;
        out0[o0 + (size_t)(c + 3) * MK] = v3;
    }
}

extern "C" void kernel_launch(void* const* d_in, const int* in_sizes, int n_in,
                              void* d_out, int out_size, void* d_ws, size_t ws_size,
                              hipStream_t stream) {
    const float* new_xyz = (const float*)d_in[0];   // (B,3,M)
    const float* xyz     = (const float*)d_in[1];   // (B,3,N)
    const float* feat    = (const float*)d_in[2];   // (B,C,N)

    const int B = 4;                       // fixed by harness setup
    const int M = in_sizes[0] / (3 * B);   // 2048
    const int N = in_sizes[1] / (3 * B);   // 8192
    const int C = in_sizes[2] / (B * N);   // 128

    const long long sz_with = (long long)B * (C + 6) * M * K_NEIGH;
    const int use_xyz = (out_size == sz_with) ? 1 : 0;

    float* out0 = (float*)d_out;
    float* out1 = out0 + (size_t)B * (use_xyz ? (C + 3) : C) * M * K_NEIGH;

    int* idxb = (int*)d_ws;  // B*M*K ints = 1 MB
    const size_t idx_bytes = (size_t)B * M * K_NEIGH * sizeof(int);

    const bool fast = (B == 4) && (N == NPTS) && (M == MQ) && (C == CCH)
                      && (ws_size >= idx_bytes);

    if (fast) {
        ball_q2_kernel<<<(B * MQ) / 16, 512, 0, stream>>>(
            xyz, new_xyz, idxb, out0, out1, use_xyz);
        gather_onepass_kernel<<<256, 1024, 0, stream>>>(feat, idxb, out0, use_xyz);
    } else {
        ball_query_xyz_kernel<<<(B * M) / 4, 256, 0, stream>>>(
            xyz, new_xyz, idxb, out0, out1, N, M, C, use_xyz);
        gather_kernel<<<B * (M / 8), 256, 0, stream>>>(xyz, new_xyz, feat, idxb,
                                                       out0, out1, N, M, C, use_xyz);
    }
}

// Round 16
// 53.460 us; speedup vs baseline: 1.2015x; 1.0696x over previous
//
#include <hip/hip_runtime.h>
#include <hip/hip_bf16.h>

// QueryGrouper: ball_query (first-K-in-index-order within radius) + grouping.
// B=4, N=8192, M=2048, C=128, K=32, radius=0.1, use_xyz from out_size.
//
// R16: ball = Q=4 queries/block x 4-way point-range split. R13/14/15 showed
// ball perf tracks occupancy (25@32w > 29@16w > 36@8w): query-only wave axis
// caps waves at 8192/Q. Splitting the POINT axis restores 8192 waves = 32/CU
// while each point is read once per 4 queries. Points come straight from L2
// (200MB = ~6us) -- no LDS staging; partial (cnt,ff,first-32) per range
// merged 4-way in LDS. Gather: R12-validated one-pass (write roofline).

#define K_NEIGH 32
// f32(0.010000000000000002) — matches JAX weak-typed radius*radius bit-exactly.
#define R2_F32 0.009999999776482582f
#define CCH 128
#define NPTS 8192
#define MQ 2048

// ---- fast-path ball: 256 thr = 4 waves; wave w = point range w*2048..+2048,
// all 4 waves share the block's 4 queries; 4-way ordered merge in LDS ----
__global__ __launch_bounds__(256, 8) void ball_split4_kernel(
    const float* __restrict__ xyz,      // (B,3,N)
    const float* __restrict__ new_xyz,  // (B,3,M)
    int* __restrict__ idxb,             // (B*M, K)
    float* __restrict__ out0,           // (B, CO, M, K)
    float* __restrict__ out1,           // (B, 3, M, K)
    int use_xyz)
{
    __shared__ int scnt[4][4];              // [range][query]
    __shared__ int sff [4][4];
    __shared__ int slidx[4][4][K_NEIGH];    // 2 KB

    const int tid  = threadIdx.x;
    const int w    = tid >> 6;         // wave id = point range
    const int lane = tid & 63;
    const int q0 = blockIdx.x * 4;     // 4 queries per block (same batch: 4|2048)
    const int b  = q0 / MQ;
    const int m0 = q0 - b * MQ;

    const float* x0 = xyz + (size_t)b * 3 * NPTS;
    const float* x1 = x0 + NPTS;
    const float* x2 = x1 + NPTS;
    const float* nb = new_xyz + (size_t)b * 3 * MQ;

    float qx[4], qy[4], qz[4];
    #pragma unroll
    for (int j = 0; j < 4; ++j) {
        qx[j] = nb[m0 + j];
        qy[j] = nb[MQ + m0 + j];
        qz[j] = nb[2 * MQ + m0 + j];
    }
    int cnt[4] = {0, 0, 0, 0};
    int ff [4] = {0, 0, 0, 0};
    const unsigned long long below = (1ull << lane) - 1ull;

    const int rbase = w * 2048;
    for (int g = 0; g < 2048; g += 64) {
        const int i = rbase + g + lane;
        const float ax = x0[i];
        const float ay = x1[i];
        const float az = x2[i];
        #pragma unroll
        for (int j = 0; j < 4; ++j) {
            // match JAX: sub, square (no FMA), left-to-right sum, all f32 RN
            const float d2 = __fadd_rn(__fadd_rn(__fmul_rn(ax - qx[j], ax - qx[j]),
                                                 __fmul_rn(ay - qy[j], ay - qy[j])),
                                       __fmul_rn(az - qz[j], az - qz[j]));
            const bool in = d2 < R2_F32;
            const unsigned long long mk = __ballot(in);
            if (mk) {
                if (cnt[j] == 0) ff[j] = rbase + g + (__ffsll(mk) - 1);
                if (in) {
                    const int pos = cnt[j] + __popcll(mk & below);
                    if (pos < K_NEIGH) slidx[w][j][pos] = i;
                }
                cnt[j] += __popcll(mk);
            }
        }
    }

    // publish partial counts/firsts (slidx already in LDS)
    if (lane < 4) {
        scnt[w][lane] = cnt[lane];
        sff [w][lane] = ff[lane];
    }
    __syncthreads();

    // merge: wave w finalizes query w. Ranges are in index order, so the
    // final list = concat(range lists)[0:K]; pad = first hit overall (or 0).
    const int jq = w;                   // 4 waves, 4 queries
    const float qxx = nb[m0 + jq];
    const float qyy = nb[MQ + m0 + jq];
    const float qzz = nb[2 * MQ + m0 + jq];

    if (lane < K_NEIGH) {
        int bacc = 0, jdx = -1, ffq = 0;
        bool ffset = false;
        #pragma unroll
        for (int r = 0; r < 4; ++r) {
            const int cr = scnt[r][jq];
            if (!ffset && cr > 0) { ffq = sff[r][jq]; ffset = true; }
            if (jdx < 0 && lane < bacc + cr) jdx = slidx[r][jq][lane - bacc];
            bacc += cr;
        }
        if (jdx < 0) jdx = ffq;   // fewer than lane+1 hits total (or none -> 0)

        const int m = m0 + jq;
        idxb[((size_t)b * MQ + m) * K_NEIGH + lane] = jdx;
        const float gx = x0[jdx] - qxx;
        const float gy = x1[jdx] - qyy;
        const float gz = x2[jdx] - qzz;
        const size_t MK = (size_t)MQ * K_NEIGH;
        const size_t o1 = (size_t)b * 3 * MK + (size_t)m * K_NEIGH + lane;
        out1[o1]          = gx;
        out1[o1 + MK]     = gy;
        out1[o1 + 2 * MK] = gz;
        if (use_xyz) {
            const size_t o0 = (size_t)b * (CCH + 3) * MK + (size_t)m * K_NEIGH + lane;
            out0[o0]          = gx;
            out0[o0 + MK]     = gy;
            out0[o0 + 2 * MK] = gz;
        }
    }
}

// ---- fallback ball (any shape): global loads, 1 query/wave ----
__global__ __launch_bounds__(256) void ball_query_xyz_kernel(
    const float* __restrict__ xyz, const float* __restrict__ new_xyz,
    int* __restrict__ idxb, float* __restrict__ out0, float* __restrict__ out1,
    int N, int M, int C, int use_xyz)
{
    __shared__ int lidx[4][K_NEIGH];
    const int wave = threadIdx.x >> 6;
    const int lane = threadIdx.x & 63;
    const int q = blockIdx.x * 4 + wave;
    const int b = q / M;
    const int m = q - b * M;

    const float* xb = xyz + (size_t)b * 3 * N;
    const float* x0 = xb;
    const float* x1 = xb + N;
    const float* x2 = xb + 2 * N;
    const float* nb = new_xyz + (size_t)b * 3 * M;
    const float qx = nb[m];
    const float qy = nb[M + m];
    const float qz = nb[2 * M + m];

    int cnt = 0;
    int ff  = 0;
    const unsigned long long below = (1ull << lane) - 1ull;

    for (int t0 = 0; t0 < N; t0 += 64) {
        const int i = t0 + lane;
        const float dx = x0[i] - qx;
        const float dy = x1[i] - qy;
        const float dz = x2[i] - qz;
        const float d2 = __fadd_rn(__fadd_rn(__fmul_rn(dx, dx), __fmul_rn(dy, dy)),
                                   __fmul_rn(dz, dz));
        const bool in_ball = d2 < R2_F32;
        const unsigned long long mask = __ballot(in_ball);
        if (mask) {
            if (cnt == 0) ff = t0 + (__ffsll(mask) - 1);
            if (in_ball) {
                const int pos = cnt + __popcll(mask & below);
                if (pos < K_NEIGH) lidx[wave][pos] = i;
            }
            cnt += __popcll(mask);
            if (cnt >= K_NEIGH) break;
        }
    }

    asm volatile("s_waitcnt lgkmcnt(0)" ::: "memory");

    if (lane < K_NEIGH) {
        const int j = (lane < cnt) ? lidx[wave][lane] : ff;
        idxb[(size_t)q * K_NEIGH + lane] = j;
        const float gx = x0[j] - qx;
        const float gy = x1[j] - qy;
        const float gz = x2[j] - qz;
        const size_t MK = (size_t)M * K_NEIGH;
        const size_t o1 = (size_t)b * 3 * MK + (size_t)m * K_NEIGH + lane;
        out1[o1]          = gx;
        out1[o1 + MK]     = gy;
        out1[o1 + 2 * MK] = gz;
        if (use_xyz) {
            const size_t o0 = (size_t)b * (C + 3) * MK + (size_t)m * K_NEIGH + lane;
            out0[o0]          = gx;
            out0[o0 + MK]     = gy;
            out0[o0 + 2 * MK] = gz;
        }
    }
}

// Fixed geometry: B=4, N=8192, M=2048, C=128. Grid = 256 blocks x 1024 thr.
// One pass, plain float4 stores (R12-validated: runs at write roofline).
__global__ __launch_bounds__(1024, 4) void gather_onepass_kernel(
    const float* __restrict__ feat,  // (B,C,N)
    const int* __restrict__ idxb,    // (B*M,K)
    float* __restrict__ out0,        // (B,CO,M,K)
    int use_xyz)
{
    __shared__ float sf[2 * NPTS];   // 64 KB: [0,N) = ch c0, [N,2N) = ch c0+1

    const int t   = threadIdx.x;
    const int bid = blockIdx.x;
    const int b   = (bid & 7) >> 1;                 // 0..3
    const int cg  = ((bid >> 3) << 1) | (bid & 1);  // 0..63
    const int c0  = cg * 2;

    // ---- Phase A: idx prefetch (regs) + feat stage (LDS) ----
    const int4* ip4 = (const int4*)(idxb + (size_t)b * MQ * K_NEIGH);
    int4 jj[16];
    #pragma unroll
    for (int i = 0; i < 16; ++i) jj[i] = ip4[i * 1024 + t];

    const float4* fv = (const float4*)(feat + ((size_t)b * CCH + c0) * NPTS);
    #pragma unroll
    for (int r = 0; r < 4; ++r)
        ((float4*)sf)[t + r * 1024] = fv[t + r * 1024];
    __syncthreads();

    // ---- Phase B: pure LDS-read + plain float4 stores ----
    const size_t MK = (size_t)MQ * K_NEIGH;
    const int CO   = use_xyz ? (CCH + 3) : CCH;
    const int coff = use_xyz ? 3 : 0;
    float* o0 = out0 + ((size_t)b * CO + coff + c0) * MK;
    float* o1 = o0 + MK;

    #pragma unroll
    for (int i = 0; i < 16; ++i) {
        const int p = i * 4096 + 4 * t;      // flat (m,k) base, k-aligned x4
        const int4 j4 = jj[i];
        float4 s0, s1;
        s0.x = sf[j4.x]; s0.y = sf[j4.y]; s0.z = sf[j4.z]; s0.w = sf[j4.w];
        s1.x = sf[NPTS + j4.x]; s1.y = sf[NPTS + j4.y];
        s1.z = sf[NPTS + j4.z]; s1.w = sf[NPTS + j4.w];
        *(float4*)(o0 + p) = s0;
        *(float4*)(o1 + p) = s1;
    }
}

// Fallback gather (any shape): R1 structure.
__global__ __launch_bounds__(256) void gather_kernel(
    const float* __restrict__ xyz, const float* __restrict__ new_xyz,
    const float* __restrict__ feat, const int* __restrict__ idxb,
    float* __restrict__ out0, float* __restrict__ out1,
    int N, int M, int C, int use_xyz)
{
    const int tid = threadIdx.x;
    const int k = tid & 31;
    const int mloc = tid >> 5;
    const int mchunks = M >> 3;
    const int b = blockIdx.x / mchunks;
    const int m = (blockIdx.x - b * mchunks) * 8 + mloc;
    const int q = b * M + m;
    const int j = idxb[(size_t)q * K_NEIGH + k];
    const size_t xb = (size_t)b * 3 * N;
    const size_t nb = (size_t)b * 3 * M;
    const float gx = xyz[xb + j]         - new_xyz[nb + m];
    const float gy = xyz[xb + N + j]     - new_xyz[nb + M + m];
    const float gz = xyz[xb + 2 * N + j] - new_xyz[nb + 2 * M + m];
    const size_t MK = (size_t)M * K_NEIGH;
    const size_t o1 = (size_t)b * 3 * MK + (size_t)m * K_NEIGH + k;
    out1[o1] = gx; out1[o1 + MK] = gy; out1[o1 + 2 * MK] = gz;
    const int CO = use_xyz ? (C + 3) : C;
    size_t o0 = (size_t)b * CO * MK + (size_t)m * K_NEIGH + k;
    if (use_xyz) {
        out0[o0] = gx; out0[o0 + MK] = gy; out0[o0 + 2 * MK] = gz;
        o0 += 3 * MK;
    }
    const float* fb = feat + (size_t)b * C * N;
    #pragma unroll 4
    for (int c = 0; c < C; c += 4) {
        const float v0 = fb[(size_t)c * N + j];
        const float v1 = fb[(size_t)(c + 1) * N + j];
        const float v2 = fb[(size_t)(c + 2) * N + j];
        const float v3 = fb[(size_t)(c + 3) * N + j];
        out0[o0 + (size_t)c * MK]       = v0;
        out0[o0 + (size_t)(c + 1) * MK] = v1;
        out0[o0 + (size_t)(c + 2) * MK] = v2;
        out0[o0 + (size_t)(c + 3) * MK] = v3;
    }
}

extern "C" void kernel_launch(void* const* d_in, const int* in_sizes, int n_in,
                              void* d_out, int out_size, void* d_ws, size_t ws_size,
                              hipStream_t stream) {
    const float* new_xyz = (const float*)d_in[0];   // (B,3,M)
    const float* xyz     = (const float*)d_in[1];   // (B,3,N)
    const float* feat    = (const float*)d_in[2];   // (B,C,N)

    const int B = 4;                       // fixed by harness setup
    const int M = in_sizes[0] / (3 * B);   // 2048
    const int N = in_sizes[1] / (3 * B);   // 8192
    const int C = in_sizes[2] / (B * N);   // 128

    const long long sz_with = (long long)B * (C + 6) * M * K_NEIGH;
    const int use_xyz = (out_size == sz_with) ? 1 : 0;

    float* out0 = (float*)d_out;
    float* out1 = out0 + (size_t)B * (use_xyz ? (C + 3) : C) * M * K_NEIGH;

    int* idxb = (int*)d_ws;  // B*M*K ints = 1 MB
    const size_t idx_bytes = (size_t)B * M * K_NEIGH * sizeof(int);

    const bool fast = (B == 4) && (N == NPTS) && (M == MQ) && (C == CCH)
                      && (ws_size >= idx_bytes);

    if (fast) {
        ball_split4_kernel<<<(B * MQ) / 4, 256, 0, stream>>>(
            xyz, new_xyz, idxb, out0, out1, use_xyz);
        gather_onepass_kernel<<<256, 1024, 0, stream>>>(feat, idxb, out0, use_xyz);
    } else {
        ball_query_xyz_kernel<<<(B * M) / 4, 256, 0, stream>>>(
            xyz, new_xyz, idxb, out0, out1, N, M, C, use_xyz);
        gather_kernel<<<B * (M / 8), 256, 0, stream>>>(xyz, new_xyz, feat, idxb,
                                                       out0, out1, N, M, C, use_xyz);
    }
}